// Round 2
// baseline (23256.189 us; speedup 1.0000x reference)
//
#include <hip/hip_runtime.h>

typedef unsigned short u16;
typedef __attribute__((ext_vector_type(8))) __bf16 bf16x8;
typedef __attribute__((ext_vector_type(4))) float f32x4;
typedef __attribute__((ext_vector_type(4))) float float4v;

#define T_SEQ 256
#define N_B   1024
#define C_IN  128
#define H_DIM 512
#define G4    2048
#define NCLS  40

union B8 { bf16x8 v; u16 s[8]; };

// ---------- bf16 split helpers ----------
__device__ __forceinline__ u16 f32_to_bf16_rne(float x) {
    unsigned u = __float_as_uint(x);
    unsigned rounding = 0x7FFFu + ((u >> 16) & 1u);
    return (u16)((u + rounding) >> 16);
}
__device__ __forceinline__ float bf16_to_f32(u16 h) {
    return __uint_as_float(((unsigned)h) << 16);
}
__device__ __forceinline__ void split2(float x, u16& hi, u16& lo) {
    u16 h = f32_to_bf16_rne(x);
    float hf = bf16_to_f32(h);
    u16 l = f32_to_bf16_rne(x - hf);
    hi = h; lo = l;
}

// ---------- prep: Wcat = [Wih | Whh], split to hi/lo bf16 planes ----------
__global__ void k_build_wcat(const float* __restrict__ Wih, const float* __restrict__ Whh,
                             int KX, u16* __restrict__ hi, u16* __restrict__ lo) {
    int K = KX + H_DIM;
    size_t idx = (size_t)blockIdx.x * 256 + threadIdx.x;
    if (idx >= (size_t)G4 * K) return;
    int g = (int)(idx / K);
    int k = (int)(idx - (size_t)g * K);
    float x = (k < KX) ? Wih[(size_t)g * KX + k] : Whh[(size_t)g * H_DIM + (k - KX)];
    u16 h, l; split2(x, h, l);
    hi[idx] = h; lo[idx] = l;
}

// ---------- fused LSTM step ----------
// G = [X | Hin] @ Wcat^T + b ; gates -> c,h update.
// Grid: 256 blocks x 256 threads. Block tile: 64 batch rows x 32 hidden cols.
// Wave q computes gate q. If Xf32 != nullptr, X is fp32 with row stride ldX
// (split to bf16 hi/lo in-register); else X is pre-split bf16 planes.
__global__ __launch_bounds__(256) void k_lstm_step(
    const float* __restrict__ Xf32, int ldX,
    const u16* __restrict__ Xhi, const u16* __restrict__ Xlo, int KX,
    const u16* __restrict__ Hhi, const u16* __restrict__ Hlo,
    const u16* __restrict__ Whi, const u16* __restrict__ Wlo, int K,
    const float* __restrict__ bias, float* __restrict__ cbuf,
    u16* __restrict__ outHhi, u16* __restrict__ outHlo,
    float* __restrict__ outH32)
{
    __shared__ float Gs[4][64][32];

    int blk = blockIdx.x;
    // XCD-locality swizzle: each XCD (blk&7) sees only 2 col-tiles -> W stays L2-resident
    int ct = ((blk & 7) << 1) | (blk >> 7);   // 0..15 col tile (32 hidden cols)
    int rt = (blk >> 3) & 15;                 // 0..15 row tile (64 batch rows)
    int n0 = rt << 6;
    int j0 = ct << 5;

    int tid  = threadIdx.x;
    int q    = tid >> 6;        // gate = wave id
    int lane = tid & 63;
    int quad = lane >> 4;
    int lr   = lane & 15;
    int koff = quad << 3;       // quad*8

    f32x4 acc[4][2];
    #pragma unroll
    for (int i = 0; i < 4; i++)
        #pragma unroll
        for (int j = 0; j < 2; j++)
            acc[i][j] = (f32x4){0.f, 0.f, 0.f, 0.f};

    for (int kt = 0; kt < K; kt += 32) {
        bf16x8 a_hi[4], a_lo[4], b_hi[2], b_lo[2];

        if (Xf32 != nullptr && kt < KX) {
            // fp32 X, split in-register
            #pragma unroll
            for (int i = 0; i < 4; i++) {
                int row = n0 + (i << 4) + lr;
                const float* p = Xf32 + (size_t)row * ldX + kt + koff;
                B8 h8, l8;
                #pragma unroll
                for (int e = 0; e < 8; e++) {
                    u16 hh, ll; split2(p[e], hh, ll);
                    h8.s[e] = hh; l8.s[e] = ll;
                }
                a_hi[i] = h8.v; a_lo[i] = l8.v;
            }
        } else {
            const u16 *ah, *al; int ld, kc;
            if (kt < KX) { ah = Xhi; al = Xlo; ld = KX;    kc = kt; }
            else         { ah = Hhi; al = Hlo; ld = H_DIM; kc = kt - KX; }
            #pragma unroll
            for (int i = 0; i < 4; i++) {
                int row = n0 + (i << 4) + lr;
                size_t o = (size_t)row * ld + kc + koff;
                a_hi[i] = *(const bf16x8*)(ah + o);
                a_lo[i] = *(const bf16x8*)(al + o);
            }
        }
        #pragma unroll
        for (int j = 0; j < 2; j++) {
            int wrow = (q << 9) + j0 + (j << 4) + lr;
            size_t o = (size_t)wrow * K + kt + koff;
            b_hi[j] = *(const bf16x8*)(Whi + o);
            b_lo[j] = *(const bf16x8*)(Wlo + o);
        }
        #pragma unroll
        for (int i = 0; i < 4; i++) {
            #pragma unroll
            for (int j = 0; j < 2; j++) {
                acc[i][j] = __builtin_amdgcn_mfma_f32_16x16x32_bf16(a_hi[i], b_hi[j], acc[i][j], 0, 0, 0);
                acc[i][j] = __builtin_amdgcn_mfma_f32_16x16x32_bf16(a_lo[i], b_hi[j], acc[i][j], 0, 0, 0);
                acc[i][j] = __builtin_amdgcn_mfma_f32_16x16x32_bf16(a_hi[i], b_lo[j], acc[i][j], 0, 0, 0);
            }
        }
    }

    // C/D layout: col = lane&15, row = quad*4 + reg
    #pragma unroll
    for (int i = 0; i < 4; i++)
        #pragma unroll
        for (int j = 0; j < 2; j++)
            #pragma unroll
            for (int r = 0; r < 4; r++)
                Gs[q][(i << 4) + (quad << 2) + r][(j << 4) + lr] = acc[i][j][r];

    __syncthreads();

    for (int e = tid; e < 64 * 32; e += 256) {
        int lrow = e >> 5, lcol = e & 31;
        int n = n0 + lrow, j = j0 + lcol;
        float gi = Gs[0][lrow][lcol] + bias[j];
        float gf = Gs[1][lrow][lcol] + bias[H_DIM + j];
        float gg = Gs[2][lrow][lcol] + bias[2 * H_DIM + j];
        float go = Gs[3][lrow][lcol] + bias[3 * H_DIM + j];
        float si = 1.f / (1.f + expf(-gi));
        float sf = 1.f / (1.f + expf(-gf));
        float so = 1.f / (1.f + expf(-go));
        int idx = (n << 9) + j;
        float cn = sf * cbuf[idx] + si * tanhf(gg);
        cbuf[idx] = cn;
        float h = so * tanhf(cn);
        u16 hh, hl; split2(h, hh, hl);
        outHhi[idx] = hh; outHlo[idx] = hl;
        if (outH32) outH32[idx] = h;
    }
}

// ---------- heads + losses ----------
__global__ __launch_bounds__(64) void k_head(
    const float* __restrict__ hfeat, const float* __restrict__ Wcls, const float* __restrict__ bcls,
    const float* __restrict__ Wbb, const float* __restrict__ bbb,
    const int* __restrict__ labels, const float* __restrict__ props,
    float* __restrict__ accum)
{
    __shared__ float hs[H_DIM];
    __shared__ float logits[NCLS];
    __shared__ float bb[2];
    int n = blockIdx.x, t = threadIdx.x;
    for (int k = t; k < H_DIM; k += 64) hs[k] = hfeat[((size_t)n << 9) + k];
    __syncthreads();
    if (t < NCLS) {
        float s = bcls[t];
        const float* w = Wcls + (size_t)t * H_DIM;
        for (int k = 0; k < H_DIM; k++) s += hs[k] * w[k];
        logits[t] = s;
    } else if (t < NCLS + 2) {
        int j = t - NCLS;
        float s = bbb[j];
        const float* w = Wbb + (size_t)j * H_DIM;
        for (int k = 0; k < H_DIM; k++) s += hs[k] * w[k];
        bb[j] = s;
    }
    __syncthreads();
    if (t == 0) {
        float m = logits[0]; int am = 0;
        for (int j = 1; j < NCLS; j++) if (logits[j] > m) { m = logits[j]; am = j; }
        float se = 0.f;
        for (int j = 0; j < NCLS; j++) se += expf(logits[j] - m);
        int lbl = labels[n * 2];
        float logp = logits[lbl] - m - logf(se);
        atomicAdd(&accum[0], -logp);
        if (am == lbl) atomicAdd(&accum[1], 1.0f);
        float s2 = 0.f;
        for (int j = 0; j < 2; j++) {
            float target = props[n * 2 + j] * (1.0f / 256.0f);
            float d = fabsf(bb[j] - target);
            s2 += (d < 1.f) ? 0.5f * d * d : d - 0.5f;
        }
        atomicAdd(&accum[2], s2);
    }
}

__global__ void k_final(const float* __restrict__ accum, float* __restrict__ out) {
    out[0] = (accum[0] * (1.0f / 1024.0f)) / (1.0f + accum[1]);
    out[1] = accum[2] * (10.0f / 2048.0f);
}

// ---------- launch ----------
extern "C" void kernel_launch(void* const* d_in, const int* in_sizes, int n_in,
                              void* d_out, int out_size, void* d_ws, size_t ws_size,
                              hipStream_t stream) {
    const float* data  = (const float*)d_in[0];
    const int*   labels= (const int*)d_in[1];
    const float* props = (const float*)d_in[2];
    const float* Wih0  = (const float*)d_in[3];
    const float* Whh0  = (const float*)d_in[4];
    const float* b0    = (const float*)d_in[5];
    const float* Wih1  = (const float*)d_in[6];
    const float* Whh1  = (const float*)d_in[7];
    const float* b1    = (const float*)d_in[8];
    const float* Wcls  = (const float*)d_in[9];
    const float* bcls  = (const float*)d_in[10];
    const float* Wbb   = (const float*)d_in[11];
    const float* bbb   = (const float*)d_in[12];
    float* out = (float*)d_out;

    char* ws = (char*)d_ws;
    size_t off = 0;
    auto alloc = [&](size_t bytes) -> void* {
        void* p = ws + off;
        off = (off + bytes + 255) & ~(size_t)255;
        return p;
    };
    const size_t NH = (size_t)N_B * H_DIM;   // 524288

    u16* Wc0_hi = (u16*)alloc((size_t)G4 * 640 * 2);
    u16* Wc0_lo = (u16*)alloc((size_t)G4 * 640 * 2);
    u16* Wc1_hi = (u16*)alloc((size_t)G4 * 1024 * 2);
    u16* Wc1_lo = (u16*)alloc((size_t)G4 * 1024 * 2);
    u16* h0_hi  = (u16*)alloc(2 * NH * 2);   // ping-pong
    u16* h0_lo  = (u16*)alloc(2 * NH * 2);
    u16* h1_hi  = (u16*)alloc(2 * NH * 2);
    u16* h1_lo  = (u16*)alloc(2 * NH * 2);
    float* c0   = (float*)alloc(NH * 4);
    float* c1   = (float*)alloc(NH * 4);
    float* bfeat= (float*)alloc(NH * 4);
    float* accum= (float*)alloc(4 * 4);
    // total ~28 MB << ws_size

    // prep
    k_build_wcat<<<(G4 * 640) / 256, 256, 0, stream>>>(Wih0, Whh0, C_IN, Wc0_hi, Wc0_lo);
    k_build_wcat<<<(G4 * 1024) / 256, 256, 0, stream>>>(Wih1, Whh1, H_DIM, Wc1_hi, Wc1_lo);

    hipMemsetAsync(h0_hi, 0, NH * 2, stream);   // slot 0 = h_{-1} = 0
    hipMemsetAsync(h0_lo, 0, NH * 2, stream);
    hipMemsetAsync(h1_hi, 0, NH * 2, stream);
    hipMemsetAsync(h1_lo, 0, NH * 2, stream);
    hipMemsetAsync(c0, 0, NH * 4, stream);
    hipMemsetAsync(c1, 0, NH * 4, stream);
    hipMemsetAsync(accum, 0, 16, stream);

    // interleaved: L0(t) then L1(t); only ping-pong h state needed
    for (int t = 0; t < T_SEQ; t++) {
        int r = t & 1, w = (t + 1) & 1;
        // layer 0: X = data[:, t, :] fp32 (row stride T*C), K = 128 + 512
        k_lstm_step<<<256, 256, 0, stream>>>(
            data + (size_t)t * C_IN, T_SEQ * C_IN,
            (const u16*)nullptr, (const u16*)nullptr, C_IN,
            h0_hi + (size_t)r * NH, h0_lo + (size_t)r * NH,
            Wc0_hi, Wc0_lo, C_IN + H_DIM,
            b0, c0,
            h0_hi + (size_t)w * NH, h0_lo + (size_t)w * NH,
            (float*)nullptr);
        // layer 1: X = h0[t] (just written, slot w), K = 512 + 512
        k_lstm_step<<<256, 256, 0, stream>>>(
            (const float*)nullptr, 0,
            h0_hi + (size_t)w * NH, h0_lo + (size_t)w * NH, H_DIM,
            h1_hi + (size_t)r * NH, h1_lo + (size_t)r * NH,
            Wc1_hi, Wc1_lo, 2 * H_DIM,
            b1, c1,
            h1_hi + (size_t)w * NH, h1_lo + (size_t)w * NH,
            (t == T_SEQ - 1) ? bfeat : (float*)nullptr);
    }

    k_head<<<N_B, 64, 0, stream>>>(bfeat, Wcls, bcls, Wbb, bbb, labels, props, accum);
    k_final<<<1, 1, 0, stream>>>(accum, out);
}

// Round 3
// 19897.675 us; speedup vs baseline: 1.1688x; 1.1688x over previous
//
#include <hip/hip_runtime.h>

typedef unsigned short u16;
typedef __attribute__((ext_vector_type(8))) __bf16 bf16x8;
typedef __attribute__((ext_vector_type(4))) float f32x4;

#define T_SEQ 256
#define N_B   1024
#define C_IN  128
#define H_DIM 512
#define G4    2048
#define NCLS  40

union B8 { bf16x8 v; u16 s[8]; };

// ---------- bf16 split helpers ----------
__device__ __forceinline__ u16 f32_to_bf16_rne(float x) {
    unsigned u = __float_as_uint(x);
    unsigned rounding = 0x7FFFu + ((u >> 16) & 1u);
    return (u16)((u + rounding) >> 16);
}
__device__ __forceinline__ float bf16_to_f32(u16 h) {
    return __uint_as_float(((unsigned)h) << 16);
}
__device__ __forceinline__ void split2(float x, u16& hi, u16& lo) {
    u16 h = f32_to_bf16_rne(x);
    float hf = bf16_to_f32(h);
    u16 l = f32_to_bf16_rne(x - hf);
    hi = h; lo = l;
}

__device__ __forceinline__ float fast_sigmoid(float x) {
    return 1.0f / (1.0f + __expf(-x));
}
__device__ __forceinline__ float fast_tanh(float x) {
    return 1.0f - 2.0f / (__expf(2.0f * x) + 1.0f);
}

// ---------- prep: Wcat = [Wih | Whh], split to hi/lo bf16 planes ----------
__global__ void k_build_wcat(const float* __restrict__ Wih, const float* __restrict__ Whh,
                             int KX, u16* __restrict__ hi, u16* __restrict__ lo) {
    int K = KX + H_DIM;
    size_t idx = (size_t)blockIdx.x * 256 + threadIdx.x;
    if (idx >= (size_t)G4 * K) return;
    int g = (int)(idx / K);
    int k = (int)(idx - (size_t)g * K);
    float x = (k < KX) ? Wih[(size_t)g * KX + k] : Whh[(size_t)g * H_DIM + (k - KX)];
    u16 h, l; split2(x, h, l);
    hi[idx] = h; lo[idx] = l;
}

// ---------- fragment bundle + pipelined GEMM core ----------
struct Frags { bf16x8 ah[4], al[4], bh[2], bl[2]; };

__device__ __forceinline__ void load_frags(Frags& F, int kt,
    const float* __restrict__ Xf32, int ldX,
    const u16* __restrict__ Xhi, const u16* __restrict__ Xlo, int KX,
    const u16* __restrict__ Hhi, const u16* __restrict__ Hlo,
    const u16* __restrict__ Whi, const u16* __restrict__ Wlo, int K,
    int n0, int j0, int q, int lr, int koff)
{
    if (Xf32 != nullptr && kt < KX) {
        // fp32 X slice, split to bf16 hi/lo in-register (only 4 of 20 k-tiles in L0)
        #pragma unroll
        for (int i = 0; i < 4; i++) {
            const float* p = Xf32 + (size_t)(n0 + (i << 4) + lr) * ldX + kt + koff;
            B8 h8, l8;
            #pragma unroll
            for (int e = 0; e < 8; e++) {
                u16 hh, ll; split2(p[e], hh, ll);
                h8.s[e] = hh; l8.s[e] = ll;
            }
            F.ah[i] = h8.v; F.al[i] = l8.v;
        }
    } else {
        const u16 *ah_, *al_; int ld, kc;
        if (kt < KX) { ah_ = Xhi; al_ = Xlo; ld = KX;    kc = kt; }
        else         { ah_ = Hhi; al_ = Hlo; ld = H_DIM; kc = kt - KX; }
        #pragma unroll
        for (int i = 0; i < 4; i++) {
            size_t o = (size_t)(n0 + (i << 4) + lr) * ld + kc + koff;
            F.ah[i] = *(const bf16x8*)(ah_ + o);
            F.al[i] = *(const bf16x8*)(al_ + o);
        }
    }
    #pragma unroll
    for (int j = 0; j < 2; j++) {
        size_t o = (size_t)((q << 9) + j0 + (j << 4) + lr) * K + kt + koff;
        F.bh[j] = *(const bf16x8*)(Whi + o);
        F.bl[j] = *(const bf16x8*)(Wlo + o);
    }
}

__device__ __forceinline__ void do_mfma(const Frags& F, f32x4 acc[4][2]) {
    #pragma unroll
    for (int i = 0; i < 4; i++)
        #pragma unroll
        for (int j = 0; j < 2; j++) {
            acc[i][j] = __builtin_amdgcn_mfma_f32_16x16x32_bf16(F.ah[i], F.bh[j], acc[i][j], 0, 0, 0);
            acc[i][j] = __builtin_amdgcn_mfma_f32_16x16x32_bf16(F.al[i], F.bh[j], acc[i][j], 0, 0, 0);
            acc[i][j] = __builtin_amdgcn_mfma_f32_16x16x32_bf16(F.ah[i], F.bl[j], acc[i][j], 0, 0, 0);
        }
}

// One LSTM step tile: block = 64 batch rows x 32 hidden cols, wave q = gate q.
__device__ __forceinline__ void lstm_step_body(
    int blk,
    const float* __restrict__ Xf32, int ldX,
    const u16* __restrict__ Xhi, const u16* __restrict__ Xlo, int KX,
    const u16* __restrict__ Hhi, const u16* __restrict__ Hlo,
    const u16* __restrict__ Whi, const u16* __restrict__ Wlo, int K,
    const float* __restrict__ bias, float* __restrict__ cbuf,
    u16* __restrict__ outHhi, u16* __restrict__ outHlo,
    float* __restrict__ outH32,
    float (*Gs)[64][32])
{
    // XCD-locality swizzle: XCD (blk&7) sees only 2 col-tiles -> W slice stays L2-resident
    int ct = ((blk & 7) << 1) | (blk >> 7);   // 0..15 col tile (32 hidden cols)
    int rt = (blk >> 3) & 15;                 // 0..15 row tile (64 batch rows)
    int n0 = rt << 6;
    int j0 = ct << 5;

    int tid  = threadIdx.x;
    int q    = tid >> 6;        // gate = wave id
    int lane = tid & 63;
    int quad = lane >> 4;
    int lr   = lane & 15;
    int koff = quad << 3;

    f32x4 acc[4][2];
    #pragma unroll
    for (int i = 0; i < 4; i++)
        #pragma unroll
        for (int j = 0; j < 2; j++)
            acc[i][j] = (f32x4){0.f, 0.f, 0.f, 0.f};

    // 2-stage register pipeline over K tiles (K/32 is even: 20 or 32)
    Frags Fa, Fb;
    int T = K >> 5;
    load_frags(Fa, 0, Xf32, ldX, Xhi, Xlo, KX, Hhi, Hlo, Whi, Wlo, K, n0, j0, q, lr, koff);
    int i = 1;
    for (; i + 1 < T; i += 2) {
        load_frags(Fb, i << 5, Xf32, ldX, Xhi, Xlo, KX, Hhi, Hlo, Whi, Wlo, K, n0, j0, q, lr, koff);
        do_mfma(Fa, acc);
        load_frags(Fa, (i + 1) << 5, Xf32, ldX, Xhi, Xlo, KX, Hhi, Hlo, Whi, Wlo, K, n0, j0, q, lr, koff);
        do_mfma(Fb, acc);
    }
    load_frags(Fb, (T - 1) << 5, Xf32, ldX, Xhi, Xlo, KX, Hhi, Hlo, Whi, Wlo, K, n0, j0, q, lr, koff);
    do_mfma(Fa, acc);
    do_mfma(Fb, acc);

    // C/D layout: col = lane&15, row = quad*4 + reg
    #pragma unroll
    for (int i2 = 0; i2 < 4; i2++)
        #pragma unroll
        for (int j2 = 0; j2 < 2; j2++)
            #pragma unroll
            for (int r = 0; r < 4; r++)
                Gs[q][(i2 << 4) + (quad << 2) + r][(j2 << 4) + lr] = acc[i2][j2][r];

    __syncthreads();

    #pragma unroll
    for (int e = 0; e < 8; e++) {
        int idx2 = e * 256 + tid;
        int lrow = idx2 >> 5, lcol = idx2 & 31;
        int n = n0 + lrow, j = j0 + lcol;
        float gi = Gs[0][lrow][lcol] + bias[j];
        float gf = Gs[1][lrow][lcol] + bias[H_DIM + j];
        float gg = Gs[2][lrow][lcol] + bias[2 * H_DIM + j];
        float go = Gs[3][lrow][lcol] + bias[3 * H_DIM + j];
        float si = fast_sigmoid(gi);
        float sf = fast_sigmoid(gf);
        float so = fast_sigmoid(go);
        int idx = (n << 9) + j;
        float cn = sf * cbuf[idx] + si * fast_tanh(gg);
        cbuf[idx] = cn;
        float h = so * fast_tanh(cn);
        u16 hh, hl; split2(h, hh, hl);
        outHhi[idx] = hh; outHlo[idx] = hl;
        if (outH32) outH32[idx] = h;
    }
}

// Layer-pipelined launch: blocks 0..255 do L0(t), blocks 256..511 do L1(t-1).
__global__ __launch_bounds__(256, 2) void k_lstm_pair(
    int t,
    const float* __restrict__ data,
    const u16* __restrict__ W0hi, const u16* __restrict__ W0lo,
    const u16* __restrict__ W1hi, const u16* __restrict__ W1lo,
    const float* __restrict__ b0, const float* __restrict__ b1,
    u16* __restrict__ h0hi, u16* __restrict__ h0lo,   // 2 slots, stride NH
    u16* __restrict__ h1hi, u16* __restrict__ h1lo,
    float* __restrict__ c0, float* __restrict__ c1,
    float* __restrict__ bfeat)
{
    __shared__ float Gs[4][64][32];
    const size_t NH = (size_t)N_B * H_DIM;

    int half = blockIdx.x >> 8;
    int blk  = blockIdx.x & 255;

    if (half == 0) {
        if (t >= T_SEQ) return;
        // L0 step t: X = data[:, t, :] fp32 (row stride T*C); H = h0[t-1]; out h0[t]
        size_t rs = (size_t)((t - 1) & 1) * NH;   // t=0 -> slot1 (zeroed)
        size_t ws = (size_t)(t & 1) * NH;
        lstm_step_body(blk,
            data + (size_t)t * C_IN, T_SEQ * C_IN,
            (const u16*)nullptr, (const u16*)nullptr, C_IN,
            h0hi + rs, h0lo + rs,
            W0hi, W0lo, C_IN + H_DIM,
            b0, c0,
            h0hi + ws, h0lo + ws,
            (float*)nullptr, Gs);
    } else {
        if (t == 0) return;
        int s = t - 1;
        // L1 step s: X = h0[s]; H = h1[s-1]; out h1[s]
        size_t xs = (size_t)(s & 1) * NH;
        size_t rs = (size_t)((s - 1) & 1) * NH;   // s=0 -> slot1 (zeroed)
        size_t ws = (size_t)(s & 1) * NH;
        lstm_step_body(blk,
            (const float*)nullptr, 0,
            h0hi + xs, h0lo + xs, H_DIM,
            h1hi + rs, h1lo + rs,
            W1hi, W1lo, 2 * H_DIM,
            b1, c1,
            h1hi + ws, h1lo + ws,
            (s == T_SEQ - 1) ? bfeat : (float*)nullptr, Gs);
    }
}

// ---------- heads + losses ----------
__global__ __launch_bounds__(64) void k_head(
    const float* __restrict__ hfeat, const float* __restrict__ Wcls, const float* __restrict__ bcls,
    const float* __restrict__ Wbb, const float* __restrict__ bbb,
    const int* __restrict__ labels, const float* __restrict__ props,
    float* __restrict__ accum)
{
    __shared__ float hs[H_DIM];
    __shared__ float logits[NCLS];
    __shared__ float bb[2];
    int n = blockIdx.x, t = threadIdx.x;
    for (int k = t; k < H_DIM; k += 64) hs[k] = hfeat[((size_t)n << 9) + k];
    __syncthreads();
    if (t < NCLS) {
        float s = bcls[t];
        const float* w = Wcls + (size_t)t * H_DIM;
        for (int k = 0; k < H_DIM; k++) s += hs[k] * w[k];
        logits[t] = s;
    } else if (t < NCLS + 2) {
        int j = t - NCLS;
        float s = bbb[j];
        const float* w = Wbb + (size_t)j * H_DIM;
        for (int k = 0; k < H_DIM; k++) s += hs[k] * w[k];
        bb[j] = s;
    }
    __syncthreads();
    if (t == 0) {
        float m = logits[0]; int am = 0;
        for (int j = 1; j < NCLS; j++) if (logits[j] > m) { m = logits[j]; am = j; }
        float se = 0.f;
        for (int j = 0; j < NCLS; j++) se += expf(logits[j] - m);
        int lbl = labels[n * 2];
        float logp = logits[lbl] - m - logf(se);
        atomicAdd(&accum[0], -logp);
        if (am == lbl) atomicAdd(&accum[1], 1.0f);
        float s2 = 0.f;
        for (int j = 0; j < 2; j++) {
            float target = props[n * 2 + j] * (1.0f / 256.0f);
            float d = fabsf(bb[j] - target);
            s2 += (d < 1.f) ? 0.5f * d * d : d - 0.5f;
        }
        atomicAdd(&accum[2], s2);
    }
}

__global__ void k_final(const float* __restrict__ accum, float* __restrict__ out) {
    out[0] = (accum[0] * (1.0f / 1024.0f)) / (1.0f + accum[1]);
    out[1] = accum[2] * (10.0f / 2048.0f);
}

// ---------- launch ----------
extern "C" void kernel_launch(void* const* d_in, const int* in_sizes, int n_in,
                              void* d_out, int out_size, void* d_ws, size_t ws_size,
                              hipStream_t stream) {
    const float* data  = (const float*)d_in[0];
    const int*   labels= (const int*)d_in[1];
    const float* props = (const float*)d_in[2];
    const float* Wih0  = (const float*)d_in[3];
    const float* Whh0  = (const float*)d_in[4];
    const float* b0    = (const float*)d_in[5];
    const float* Wih1  = (const float*)d_in[6];
    const float* Whh1  = (const float*)d_in[7];
    const float* b1    = (const float*)d_in[8];
    const float* Wcls  = (const float*)d_in[9];
    const float* bcls  = (const float*)d_in[10];
    const float* Wbb   = (const float*)d_in[11];
    const float* bbb   = (const float*)d_in[12];
    float* out = (float*)d_out;

    char* ws = (char*)d_ws;
    size_t off = 0;
    auto alloc = [&](size_t bytes) -> void* {
        void* p = ws + off;
        off = (off + bytes + 255) & ~(size_t)255;
        return p;
    };
    const size_t NH = (size_t)N_B * H_DIM;   // 524288

    u16* Wc0_hi = (u16*)alloc((size_t)G4 * 640 * 2);
    u16* Wc0_lo = (u16*)alloc((size_t)G4 * 640 * 2);
    u16* Wc1_hi = (u16*)alloc((size_t)G4 * 1024 * 2);
    u16* Wc1_lo = (u16*)alloc((size_t)G4 * 1024 * 2);
    u16* h0_hi  = (u16*)alloc(2 * NH * 2);   // ping-pong slots
    u16* h0_lo  = (u16*)alloc(2 * NH * 2);
    u16* h1_hi  = (u16*)alloc(2 * NH * 2);
    u16* h1_lo  = (u16*)alloc(2 * NH * 2);
    float* c0   = (float*)alloc(NH * 4);
    float* c1   = (float*)alloc(NH * 4);
    float* bfeat= (float*)alloc(NH * 4);
    float* accum= (float*)alloc(4 * 4);
    // total ~28 MB

    // prep
    k_build_wcat<<<(G4 * 640) / 256, 256, 0, stream>>>(Wih0, Whh0, C_IN, Wc0_hi, Wc0_lo);
    k_build_wcat<<<(G4 * 1024) / 256, 256, 0, stream>>>(Wih1, Whh1, H_DIM, Wc1_hi, Wc1_lo);

    // zero slot 1 (h[-1]) and both c states
    hipMemsetAsync(h0_hi + NH, 0, NH * 2, stream);
    hipMemsetAsync(h0_lo + NH, 0, NH * 2, stream);
    hipMemsetAsync(h1_hi + NH, 0, NH * 2, stream);
    hipMemsetAsync(h1_lo + NH, 0, NH * 2, stream);
    hipMemsetAsync(c0, 0, NH * 4, stream);
    hipMemsetAsync(c1, 0, NH * 4, stream);
    hipMemsetAsync(accum, 0, 16, stream);

    // layer-pipelined: launch t computes L0(t) and L1(t-1) concurrently
    for (int t = 0; t <= T_SEQ; t++) {
        k_lstm_pair<<<512, 256, 0, stream>>>(
            t, data,
            Wc0_hi, Wc0_lo, Wc1_hi, Wc1_lo,
            b0, b1,
            h0_hi, h0_lo, h1_hi, h1_lo,
            c0, c1, bfeat);
    }

    k_head<<<N_B, 64, 0, stream>>>(bfeat, Wcls, bcls, Wbb, bbb, labels, props, accum);
    k_final<<<1, 1, 0, stream>>>(accum, out);
}

// Round 5
// 8896.156 us; speedup vs baseline: 2.6142x; 2.2367x over previous
//
#include <hip/hip_runtime.h>

typedef unsigned short u16;
typedef __attribute__((ext_vector_type(8))) __bf16 bf16x8;
typedef __attribute__((ext_vector_type(4))) float f32x4;

#define T_SEQ 256
#define N_B   1024
#define C_IN  128
#define H_DIM 512
#define NCLS  40
#define NT0   20
#define NT1   32
#define HSLOT (16*1024*32)   // u16 elems per hpack slot

union B8 { bf16x8 v; u16 s[8]; };

// ---------- bf16 split helpers ----------
__device__ __forceinline__ u16 f32_to_bf16_rne(float x) {
    unsigned u = __float_as_uint(x);
    unsigned rounding = 0x7FFFu + ((u >> 16) & 1u);
    return (u16)((u + rounding) >> 16);
}
__device__ __forceinline__ float bf16_to_f32(u16 h) {
    return __uint_as_float(((unsigned)h) << 16);
}
__device__ __forceinline__ void split2(float x, u16& hi, u16& lo) {
    u16 h = f32_to_bf16_rne(x);
    float hf = bf16_to_f32(h);
    u16 l = f32_to_bf16_rne(x - hf);
    hi = h; lo = l;
}
__device__ __forceinline__ float fast_sigmoid(float x) {
    return 1.0f / (1.0f + __expf(-x));
}
__device__ __forceinline__ float fast_tanh(float x) {
    return 1.0f - 2.0f / (__expf(2.0f * x) + 1.0f);
}

// ---------- prep: pack W into per-(ct,kt) fragment blocks ----------
// layout: idx = ((ct*NT + kt)*128 + r)*32 + k ; r = 4*jl + gate
__global__ void k_pack_w(const float* __restrict__ Wih, const float* __restrict__ Whh,
                         int KX, int NT, u16* __restrict__ hi, u16* __restrict__ lo) {
    size_t idx = (size_t)blockIdx.x * 256 + threadIdx.x;
    size_t total = (size_t)16 * NT * 128 * 32;
    if (idx >= total) return;
    int k = (int)(idx & 31);
    int r = (int)((idx >> 5) & 127);
    int rem = (int)(idx >> 12);
    int kt = rem % NT, ct = rem / NT;
    int gate = r & 3, jl = r >> 2;
    int srow = (gate << 9) + (ct << 5) + jl;
    int kg = (kt << 5) + k;
    float v = (kg < KX) ? Wih[(size_t)srow * KX + kg] : Whh[(size_t)srow * H_DIM + (kg - KX)];
    u16 h, l; split2(v, h, l);
    hi[idx] = h; lo[idx] = l;
}

// ---------- LSTM step tile body: block = 128 batch x 128 G'-cols, 8 waves ----------
__device__ __forceinline__ void lstm_tile_body(
    int local_blk,
    const float* __restrict__ Xf32,                       // L0: data + t*C (row stride 32768), else null
    const u16* __restrict__ xAhi, const u16* __restrict__ xAlo, int nxt,
    const u16* __restrict__ hAhi, const u16* __restrict__ hAlo,
    const u16* __restrict__ Whi, const u16* __restrict__ Wlo, int NT,
    const float* __restrict__ bias, float* __restrict__ cbuf,
    u16* __restrict__ oHhi, u16* __restrict__ oHlo, float* __restrict__ oF32,
    char* lds, float* biasT)
{
    // XCD swizzle: same-XCD blocks share 2 col-tiles -> W slice stays L2-resident
    int ct = ((blockIdx.x & 7) << 1) | ((local_blk >> 6) & 1);  // 0..15
    int rt = (local_blk >> 3) & 7;                              // 0..7
    int n0 = rt << 7;

    int tid  = threadIdx.x;
    int w    = tid >> 6;
    int l    = tid & 63;
    int quad = l >> 4;
    int lr   = l & 15;
    int wr   = (w & 1) << 6;     // 0 or 64
    int wc   = (w >> 1) << 5;    // 0,32,64,96

    if (tid < 128)
        biasT[tid] = bias[((tid & 3) << 9) + (ct << 5) + (tid >> 2)];

    const size_t wbase = ((size_t)(ct * NT)) << 12;
    bf16x8 sa_h, sa_l, sb_h, sb_l;

    auto load_stage = [&](int kt) {
        size_t wo = wbase + ((size_t)kt << 12) + ((size_t)tid << 3);
        sb_h = *(const bf16x8*)(Whi + wo);
        sb_l = *(const bf16x8*)(Wlo + wo);
        if (Xf32 != nullptr && kt < nxt) {
            int row = tid >> 2, seg = tid & 3;
            const float* p = Xf32 + (size_t)(n0 + row) * 32768 + (kt << 5) + (seg << 3);
            f32x4 x0 = *(const f32x4*)p;
            f32x4 x1 = *(const f32x4*)(p + 4);
            B8 hh, ll;
            #pragma unroll
            for (int e = 0; e < 4; e++) { u16 a, b; split2(x0[e], a, b); hh.s[e] = a; ll.s[e] = b; }
            #pragma unroll
            for (int e = 0; e < 4; e++) { u16 a, b; split2(x1[e], a, b); hh.s[4 + e] = a; ll.s[4 + e] = b; }
            sa_h = hh.v; sa_l = ll.v;
        } else {
            const u16 *ph, *pl; int kk;
            if (kt < nxt) { ph = xAhi; pl = xAlo; kk = kt; }
            else          { ph = hAhi; pl = hAlo; kk = kt - nxt; }
            size_t ao = (((size_t)kk * 1024 + n0) << 5) + ((size_t)tid << 3);
            sa_h = *(const bf16x8*)(ph + ao);
            sa_l = *(const bf16x8*)(pl + ao);
        }
    };
    auto write_stage = [&](char* buf) {
        *(bf16x8*)(buf + (tid << 4))         = sa_h;
        *(bf16x8*)(buf + 8192 + (tid << 4))  = sa_l;
        *(bf16x8*)(buf + 16384 + (tid << 4)) = sb_h;
        *(bf16x8*)(buf + 24576 + (tid << 4)) = sb_l;
    };

    f32x4 acc[4][2];
    #pragma unroll
    for (int i = 0; i < 4; i++)
        #pragma unroll
        for (int j = 0; j < 2; j++)
            acc[i][j] = (f32x4){0.f, 0.f, 0.f, 0.f};

    load_stage(0);
    write_stage(lds);
    __syncthreads();

    for (int tt = 0; tt < NT; tt++) {
        char* cur = lds + ((tt & 1) << 15);
        if (tt + 1 < NT) load_stage(tt + 1);

        bf16x8 ah[4], al[4], bh[2], bl[2];
        #pragma unroll
        for (int i = 0; i < 4; i++) {
            int ro = (wr + (i << 4) + lr) << 6;
            ah[i] = *(const bf16x8*)(cur + ro + (quad << 4));
            al[i] = *(const bf16x8*)(cur + 8192 + ro + (quad << 4));
        }
        #pragma unroll
        for (int j = 0; j < 2; j++) {
            int ro = (wc + (j << 4) + lr) << 6;
            bh[j] = *(const bf16x8*)(cur + 16384 + ro + (quad << 4));
            bl[j] = *(const bf16x8*)(cur + 24576 + ro + (quad << 4));
        }
        #pragma unroll
        for (int i = 0; i < 4; i++)
            #pragma unroll
            for (int j = 0; j < 2; j++) {
                acc[i][j] = __builtin_amdgcn_mfma_f32_16x16x32_bf16(ah[i], bh[j], acc[i][j], 0, 0, 0);
                acc[i][j] = __builtin_amdgcn_mfma_f32_16x16x32_bf16(al[i], bh[j], acc[i][j], 0, 0, 0);
                acc[i][j] = __builtin_amdgcn_mfma_f32_16x16x32_bf16(ah[i], bl[j], acc[i][j], 0, 0, 0);
            }

        if (tt + 1 < NT) write_stage(lds + (((tt + 1) & 1) << 15));
        __syncthreads();
    }

    // dump G' (128x128 fp32) to LDS; C/D layout: col = lane&15, row = quad*4 + reg
    float* Gs = (float*)lds;
    #pragma unroll
    for (int i = 0; i < 4; i++)
        #pragma unroll
        for (int j2 = 0; j2 < 2; j2++)
            #pragma unroll
            for (int r = 0; r < 4; r++)
                Gs[(wr + (i << 4) + (quad << 2) + r) * 128 + wc + (j2 << 4) + lr] = acc[i][j2][r];
    __syncthreads();

    // epilogue: G' cols are 4*jl + gate
    int jl = tid & 31;
    int rbase = tid >> 5;
    #pragma unroll
    for (int it = 0; it < 8; it++) {
        int row = rbase + (it << 4);
        f32x4 gv = *(const f32x4*)(Gs + row * 128 + (jl << 2));
        float gi = gv[0] + biasT[(jl << 2) + 0];
        float gf = gv[1] + biasT[(jl << 2) + 1];
        float gg = gv[2] + biasT[(jl << 2) + 2];
        float go = gv[3] + biasT[(jl << 2) + 3];
        float si = fast_sigmoid(gi);
        float sf = fast_sigmoid(gf);
        float so = fast_sigmoid(go);
        int n = n0 + row;
        int cidx = (n << 9) + (ct << 5) + jl;
        float cn = sf * cbuf[cidx] + si * fast_tanh(gg);
        cbuf[cidx] = cn;
        float h = so * fast_tanh(cn);
        u16 hh2, hl2; split2(h, hh2, hl2);
        size_t ho = (((size_t)ct * 1024 + n) << 5) + jl;
        oHhi[ho] = hh2; oHlo[ho] = hl2;
        if (oF32) oF32[cidx] = h;
    }
}

// blocks 0..127: L1(t-1); blocks 128..255: L0(t)
__global__ __launch_bounds__(512) void k_lstm_pair(
    int t, const float* __restrict__ data,
    const u16* __restrict__ W0hi, const u16* __restrict__ W0lo,
    const u16* __restrict__ W1hi, const u16* __restrict__ W1lo,
    const float* __restrict__ b0, const float* __restrict__ b1,
    u16* __restrict__ h0hi, u16* __restrict__ h0lo,
    u16* __restrict__ h1hi, u16* __restrict__ h1lo,
    float* __restrict__ c0, float* __restrict__ c1,
    float* __restrict__ bfeat)
{
    __shared__ __align__(16) char lds[84096];   // >81920 -> 1 block/CU spread
    __shared__ float biasT[128];
    int local_blk = blockIdx.x & 127;

    if (blockIdx.x < 128) {
        if (t == 0) return;
        int s = t - 1;
        const u16* xh = h0hi + (size_t)(s & 1) * HSLOT;
        const u16* xl = h0lo + (size_t)(s & 1) * HSLOT;
        const u16* hh = h1hi + (size_t)((s - 1) & 1) * HSLOT;
        const u16* hl = h1lo + (size_t)((s - 1) & 1) * HSLOT;
        u16* oh = h1hi + (size_t)(s & 1) * HSLOT;
        u16* ol = h1lo + (size_t)(s & 1) * HSLOT;
        lstm_tile_body(local_blk, nullptr, xh, xl, 16, hh, hl,
                       W1hi, W1lo, NT1, b1, c1, oh, ol,
                       (s == T_SEQ - 1) ? bfeat : nullptr, lds, biasT);
    } else {
        if (t >= T_SEQ) return;
        const u16* hh = h0hi + (size_t)((t - 1) & 1) * HSLOT;
        const u16* hl = h0lo + (size_t)((t - 1) & 1) * HSLOT;
        u16* oh = h0hi + (size_t)(t & 1) * HSLOT;
        u16* ol = h0lo + (size_t)(t & 1) * HSLOT;
        lstm_tile_body(local_blk, data + (size_t)t * C_IN, nullptr, nullptr, 4,
                       hh, hl, W0hi, W0lo, NT0, b0, c0, oh, ol,
                       nullptr, lds, biasT);
    }
}

// ---------- heads + losses ----------
__global__ __launch_bounds__(64) void k_head(
    const float* __restrict__ hfeat, const float* __restrict__ Wcls, const float* __restrict__ bcls,
    const float* __restrict__ Wbb, const float* __restrict__ bbb,
    const int* __restrict__ labels, const float* __restrict__ props,
    float* __restrict__ accum)
{
    __shared__ float hs[H_DIM];
    __shared__ float logits[NCLS];
    __shared__ float bb[2];
    int n = blockIdx.x, t = threadIdx.x;
    for (int k = t; k < H_DIM; k += 64) hs[k] = hfeat[((size_t)n << 9) + k];
    __syncthreads();
    if (t < NCLS) {
        float s = bcls[t];
        const float* w = Wcls + (size_t)t * H_DIM;
        for (int k = 0; k < H_DIM; k++) s += hs[k] * w[k];
        logits[t] = s;
    } else if (t < NCLS + 2) {
        int j = t - NCLS;
        float s = bbb[j];
        const float* w = Wbb + (size_t)j * H_DIM;
        for (int k = 0; k < H_DIM; k++) s += hs[k] * w[k];
        bb[j] = s;
    }
    __syncthreads();
    if (t == 0) {
        float m = logits[0]; int am = 0;
        for (int j = 1; j < NCLS; j++) if (logits[j] > m) { m = logits[j]; am = j; }
        float se = 0.f;
        for (int j = 0; j < NCLS; j++) se += expf(logits[j] - m);
        int lbl = labels[n * 2];
        float logp = logits[lbl] - m - logf(se);
        atomicAdd(&accum[0], -logp);
        if (am == lbl) atomicAdd(&accum[1], 1.0f);
        float s2 = 0.f;
        for (int j = 0; j < 2; j++) {
            float target = props[n * 2 + j] * (1.0f / 256.0f);
            float d = fabsf(bb[j] - target);
            s2 += (d < 1.f) ? 0.5f * d * d : d - 0.5f;
        }
        atomicAdd(&accum[2], s2);
    }
}

__global__ void k_final(const float* __restrict__ accum, float* __restrict__ out) {
    out[0] = (accum[0] * (1.0f / 1024.0f)) / (1.0f + accum[1]);
    out[1] = accum[2] * (10.0f / 2048.0f);
}

// ---------- launch ----------
extern "C" void kernel_launch(void* const* d_in, const int* in_sizes, int n_in,
                              void* d_out, int out_size, void* d_ws, size_t ws_size,
                              hipStream_t stream) {
    const float* data  = (const float*)d_in[0];
    const int*   labels= (const int*)d_in[1];
    const float* props = (const float*)d_in[2];
    const float* Wih0  = (const float*)d_in[3];
    const float* Whh0  = (const float*)d_in[4];
    const float* b0    = (const float*)d_in[5];
    const float* Wih1  = (const float*)d_in[6];
    const float* Whh1  = (const float*)d_in[7];
    const float* b1    = (const float*)d_in[8];
    const float* Wcls  = (const float*)d_in[9];
    const float* bcls  = (const float*)d_in[10];
    const float* Wbb   = (const float*)d_in[11];
    const float* bbb   = (const float*)d_in[12];
    float* out = (float*)d_out;

    char* ws = (char*)d_ws;
    size_t off = 0;
    auto alloc = [&](size_t bytes) -> void* {
        void* p = ws + off;
        off = (off + bytes + 255) & ~(size_t)255;
        return p;
    };
    const size_t NH = (size_t)N_B * H_DIM;
    const size_t W0E = (size_t)16 * NT0 * 128 * 32;   // 1,310,720
    const size_t W1E = (size_t)16 * NT1 * 128 * 32;   // 2,097,152

    u16* W0hi = (u16*)alloc(W0E * 2);
    u16* W0lo = (u16*)alloc(W0E * 2);
    u16* W1hi = (u16*)alloc(W1E * 2);
    u16* W1lo = (u16*)alloc(W1E * 2);
    u16* h0hi = (u16*)alloc(2 * (size_t)HSLOT * 2);
    u16* h0lo = (u16*)alloc(2 * (size_t)HSLOT * 2);
    u16* h1hi = (u16*)alloc(2 * (size_t)HSLOT * 2);
    u16* h1lo = (u16*)alloc(2 * (size_t)HSLOT * 2);
    float* c0   = (float*)alloc(NH * 4);
    float* c1   = (float*)alloc(NH * 4);
    float* bfeat= (float*)alloc(NH * 4);
    float* accum= (float*)alloc(4 * 4);

    k_pack_w<<<(int)(W0E / 256), 256, 0, stream>>>(Wih0, Whh0, C_IN, NT0, W0hi, W0lo);
    k_pack_w<<<(int)(W1E / 256), 256, 0, stream>>>(Wih1, Whh1, H_DIM, NT1, W1hi, W1lo);

    (void)hipMemsetAsync(h0hi + HSLOT, 0, (size_t)HSLOT * 2, stream);
    (void)hipMemsetAsync(h0lo + HSLOT, 0, (size_t)HSLOT * 2, stream);
    (void)hipMemsetAsync(h1hi + HSLOT, 0, (size_t)HSLOT * 2, stream);
    (void)hipMemsetAsync(h1lo + HSLOT, 0, (size_t)HSLOT * 2, stream);
    (void)hipMemsetAsync(c0, 0, NH * 4, stream);
    (void)hipMemsetAsync(c1, 0, NH * 4, stream);
    (void)hipMemsetAsync(accum, 0, 16, stream);

    for (int t = 0; t <= T_SEQ; t++) {
        k_lstm_pair<<<256, 512, 0, stream>>>(
            t, data, W0hi, W0lo, W1hi, W1lo, b0, b1,
            h0hi, h0lo, h1hi, h1lo, c0, c1, bfeat);
    }

    k_head<<<N_B, 64, 0, stream>>>(bfeat, Wcls, bcls, Wbb, bbb, labels, props, accum);
    k_final<<<1, 1, 0, stream>>>(accum, out);
}